// Round 10
// baseline (203.360 us; speedup 1.0000x reference)
//
#include <hip/hip_runtime.h>
#include <stdint.h>

typedef __attribute__((ext_vector_type(8))) short bf16x8;
typedef __attribute__((ext_vector_type(4))) short bf16x4;
typedef __attribute__((ext_vector_type(4))) float f32x4;

#define WAVES 4
// Per-wave LDS (shorts):
//  rf : fp32 double buffer, 2 x 1024 floats (2 x 16 rows x 64 c), filled by
//       global_load_lds (linear: float idx = chunkgrp*256 + row*16 + chunk*4+e).
//  cn : [64 c][32 n] bf16 stride 36 (r8-verified) for GEMM2-B (2 x b64 reads).
//  a  : [32 k][40] softmax weights (r4+-verified).
#define RF_FLOATS 1024
#define RF_SHORTS (2 * RF_FLOATS * 2)  // 4096 shorts = 8192 B
#define CN_STRIDE 36
#define CN_SHORTS (64 * CN_STRIDE)     // 2304
#define A_STRIDE 40
#define A_SHORTS (32 * A_STRIDE)       // 1280
#define WAVE_LDS (RF_SHORTS + CN_SHORTS + A_SHORTS)  // 7680 shorts = 15360 B
#define W_LDS_OFF (WAVES * WAVE_LDS)   // 30720 shorts
#define SMEM_SHORTS (W_LDS_OFF + 2048) // 32768 shorts = 65536 B (2 blocks/CU)
#define VB_STRIDE 68
#define WS_STRIDE 2080

// ROUND-10 THESIS: every prior variant loaded R with dest-register loads
// inside dependent phases; under the VGPR squeeze the compiler serializes
// them (load->waitcnt->use chains), so each wave eats ~4 serial HBM
// latencies per phase -- consistent with ALL pipes <11% busy, ~2 TB/s
// plateau, and the r7/r8 nulls. Fix: fire-and-forget global_load_lds with
// counted vmcnt(4) (T3/T4): 8 loads (8 KB) permanently in flight per wave,
// waits never drain to 0 mid-loop.

static __device__ __forceinline__ void gload16(const float* g, float* l) {
    __builtin_amdgcn_global_load_lds(
        (const __attribute__((address_space(1))) void*)g,
        (__attribute__((address_space(3))) void*)l, 16, 0, 0);
}

static __device__ __forceinline__ bf16x8 cvt8(float4 a, float4 b) {
    union { int i[4]; bf16x8 v; } u;
    asm("v_cvt_pk_bf16_f32 %0, %1, %2" : "=v"(u.i[0]) : "v"(a.x), "v"(a.y));
    asm("v_cvt_pk_bf16_f32 %0, %1, %2" : "=v"(u.i[1]) : "v"(a.z), "v"(a.w));
    asm("v_cvt_pk_bf16_f32 %0, %1, %2" : "=v"(u.i[2]) : "v"(b.x), "v"(b.y));
    asm("v_cvt_pk_bf16_f32 %0, %1, %2" : "=v"(u.i[3]) : "v"(b.z), "v"(b.w));
    return u.v;
}

// Sum across the 16 lanes of a DPP row (all lanes end with the total).
static __device__ __forceinline__ float row_sum16(float x) {
    union fi { float f; int i; };
    fi a, b; a.f = x;
    b.i = __builtin_amdgcn_mov_dpp(a.i, 0x128, 0xf, 0xf, false); a.f += b.f;
    b.i = __builtin_amdgcn_mov_dpp(a.i, 0x124, 0xf, 0xf, false); a.f += b.f;
    b.i = __builtin_amdgcn_mov_dpp(a.i, 0x122, 0xf, 0xf, false); a.f += b.f;
    b.i = __builtin_amdgcn_mov_dpp(a.i, 0x121, 0xf, 0xf, false); a.f += b.f;
    return a.f;
}

#define WAITV(N) do { \
    asm volatile("s_waitcnt vmcnt(" #N ")" ::: "memory"); \
    __builtin_amdgcn_sched_barrier(0); } while(0)

// issue one 16-row phase (4 x global_load_lds, 1 KB each instr):
// instr i covers global chunks (lane&3)+4i of row (lane>>2); LDS dest
// linear lb + i*256 floats (+ lane*16B by HW).
#define ISSUE(it_, s_) do { \
    const float* g_ = gbase + (size_t)(((it_)*128 + (s_)*16) * 64); \
    float* l_ = rf + (s_)*RF_FLOATS; \
    gload16(g_,      l_      ); \
    gload16(g_ + 16, l_ + 256); \
    gload16(g_ + 32, l_ + 512); \
    gload16(g_ + 48, l_ + 768); \
} while(0)

// consume phase s_: extract af frags from the fp32 image (2 x b128 each,
// contiguous by the gload layout), cvt once, transpose-scatter cn, then
// (optionally) re-issue into the freed buffer, then GEMM1 + softmax.
#define PHASE(s_, ...) do { \
    const float* lb_ = rf + (s_)*RF_FLOATS; \
    const float* ap_ = lb_ + (quad>>1)*256 + l15*16 + (quad&1)*8; \
    const float4 f0_ = *(const float4*)(ap_); \
    const float4 f1_ = *(const float4*)(ap_ + 4); \
    const float4 f2_ = *(const float4*)(ap_ + 512); \
    const float4 f3_ = *(const float4*)(ap_ + 516); \
    const bf16x8 af0_ = cvt8(f0_, f1_); \
    const bf16x8 af1_ = cvt8(f2_, f3_); \
    { const int n_ = (s_)*16 + l15; \
      _Pragma("unroll") \
      for (int e = 0; e < 8; ++e) { \
          cn_lds[(quad*8 + e)*CN_STRIDE + n_]      = af0_[e]; \
          cn_lds[(32 + quad*8 + e)*CN_STRIDE + n_] = af1_[e]; } } \
    __builtin_amdgcn_sched_barrier(0); \
    __VA_ARGS__; \
    f32x4 d1s_[2]; \
    _Pragma("unroll") \
    for (int kt = 0; kt < 2; ++kt) { \
        const int k_ = kt*16 + l15; \
        const bf16x8 w0_ = *(const bf16x8*)(w_lds + k_*64 + ((quad*8)      ^ ((k_ & 7) << 3))); \
        const bf16x8 w1_ = *(const bf16x8*)(w_lds + k_*64 + ((32 + quad*8) ^ ((k_ & 7) << 3))); \
        f32x4 d_ = (f32x4){0.f, 0.f, 0.f, 0.f}; \
        d_ = __builtin_amdgcn_mfma_f32_16x16x32_bf16(af0_, w0_, d_, 0, 0, 0); \
        d_ = __builtin_amdgcn_mfma_f32_16x16x32_bf16(af1_, w1_, d_, 0, 0, 0); \
        d1s_[kt] = d_; } \
    float a0v_[4], a1v_[4]; float a0s_ = 0.f, a1s_ = 0.f; \
    _Pragma("unroll") \
    for (int r = 0; r < 4; ++r) { \
        float l0_ = d1s_[0][r] + bval[0]; \
        float l1_ = d1s_[1][r] + bval[1]; \
        float e0_ = __expf(l0_), e1_ = __expf(l1_); \
        float ss_ = row_sum16(e0_ + e1_); \
        float rs_ = __builtin_amdgcn_rcpf(ss_); \
        a0v_[r] = e0_ * rs_; a1v_[r] = e1_ * rs_; \
        a0s_ += a0v_[r]; a1s_ += a1v_[r]; } \
    suma[0] += a0s_; suma[1] += a1s_; \
    union { int i[2]; bf16x4 v; } p0_, p1_; \
    asm("v_cvt_pk_bf16_f32 %0, %1, %2" : "=v"(p0_.i[0]) : "v"(a0v_[0]), "v"(a0v_[1])); \
    asm("v_cvt_pk_bf16_f32 %0, %1, %2" : "=v"(p0_.i[1]) : "v"(a0v_[2]), "v"(a0v_[3])); \
    asm("v_cvt_pk_bf16_f32 %0, %1, %2" : "=v"(p1_.i[0]) : "v"(a1v_[0]), "v"(a1v_[1])); \
    asm("v_cvt_pk_bf16_f32 %0, %1, %2" : "=v"(p1_.i[1]) : "v"(a1v_[2]), "v"(a1v_[3])); \
    *(bf16x4*)(a_lds + l15*A_STRIDE        + (s_)*16 + quad*4) = p0_.v; \
    *(bf16x4*)(a_lds + (16 + l15)*A_STRIDE + (s_)*16 + quad*4) = p1_.v; \
} while(0)

#define GEMM2 do { \
    __builtin_amdgcn_sched_barrier(0); \
    bf16x8 a2_[2]; \
    _Pragma("unroll") \
    for (int kt = 0; kt < 2; ++kt) \
        a2_[kt] = *(bf16x8*)(a_lds + (kt*16 + l15)*A_STRIDE + quad*8); \
    _Pragma("unroll") \
    for (int ct = 0; ct < 4; ++ct) { \
        const short* bp_ = cn_lds + (ct*16 + l15)*CN_STRIDE + quad*8; \
        union { bf16x4 h2[2]; bf16x8 v; } b2_; \
        b2_.h2[0] = *(const bf16x4*)bp_; \
        b2_.h2[1] = *(const bf16x4*)(bp_ + 4); \
        _Pragma("unroll") \
        for (int k2 = 0; k2 < 2; ++k2) \
            acc[k2][ct] = __builtin_amdgcn_mfma_f32_16x16x32_bf16(a2_[k2], b2_.v, acc[k2][ct], 0, 0, 0); } \
    __builtin_amdgcn_sched_barrier(0); \
} while(0)

__global__ __launch_bounds__(256, 2)
void netvlad_partial(const float* __restrict__ R,
                     const float* __restrict__ W,
                     const float* __restrict__ bias,
                     float* __restrict__ ws)
{
    __shared__ short smem[SMEM_SHORTS];   // 65536 B exactly -> 2 blocks/CU

    const int tid  = threadIdx.x;
    const int wave = tid >> 6;
    const int lane = tid & 63;
    const int l15  = lane & 15;
    const int quad = lane >> 4;
    const int bid  = blockIdx.x;
    const int m    = bid >> 3;
    const int h    = bid & 7;

    short* wbase  = smem + wave * WAVE_LDS;
    float* rf     = (float*)wbase;                 // 2 x 1024 floats
    short* cn_lds = wbase + RF_SHORTS;
    short* a_lds  = wbase + RF_SHORTS + CN_SHORTS;
    short* w_lds  = smem + W_LDS_OFF;

    const float* Rm = R + ((size_t)m * 2048 + (size_t)h * 256) * 64;

    // Stage W (32x64) as bf16 into shared LDS (verified rounds 4-9).
#pragma unroll
    for (int kt = 0; kt < 2; ++kt)
#pragma unroll
        for (int cc = 0; cc < 2; ++cc) {
            const int k = kt*16 + l15;
            const int c = cc*32 + quad*8;
            const float* wp = W + k*64 + c;
            bf16x8 wv = cvt8(*(const float4*)wp, *(const float4*)(wp + 4));
            *(bf16x8*)(w_lds + k*64 + (c ^ ((k & 7) << 3))) = wv;
        }

    float bval[2];
    bval[0] = bias[l15];
    bval[1] = bias[16 + l15];

    f32x4 acc[2][4];
#pragma unroll
    for (int kt = 0; kt < 2; ++kt)
#pragma unroll
        for (int ct = 0; ct < 4; ++ct)
            acc[kt][ct] = (f32x4){0.f, 0.f, 0.f, 0.f};
    float suma[2] = {0.f, 0.f};

    // coalesced gload base: lane -> row lane>>2, chunk lane&3 (r9-verified map)
    const float* gbase = Rm + (size_t)(wave*32 + (lane >> 2))*64 + (lane & 3)*4;

    // Drain compiler-issued VMEM (W, bias) so vmcnt counts ONLY gload_lds.
    asm volatile("s_waitcnt vmcnt(0)" ::: "memory");
    __builtin_amdgcn_sched_barrier(0);

    // Pipeline: phases P(it,s); 8 loads in flight at all times.
    ISSUE(0, 0);
    ISSUE(0, 1);

    WAITV(4);  PHASE(0, ISSUE(1, 0));   // consume P(0,0); refill b0 with P(1,0)
    WAITV(4);  PHASE(1, ISSUE(1, 1));   // consume P(0,1); refill b1 with P(1,1)
    GEMM2;                              // iteration 0 accumulate
    WAITV(4);  PHASE(0, (void)0);       // consume P(1,0)
    WAITV(0);  PHASE(1, (void)0);       // consume P(1,1)
    GEMM2;                              // iteration 1 accumulate

    // suma: fold the 4 quads together
#pragma unroll
    for (int kt = 0; kt < 2; ++kt) {
        suma[kt] += __shfl_xor(suma[kt], 16);
        suma[kt] += __shfl_xor(suma[kt], 32);
    }

    // cross-wave log-tree reduction (aliases dead staging LDS / W region)
    float* vbuf = (float*)smem;
    float* suma_buf = (float*)(smem + W_LDS_OFF);
    __syncthreads();
#pragma unroll
    for (int step = 2; step >= 1; step >>= 1) {
        if (wave >= step && wave < 2*step) {
            float* dst = vbuf + (wave - step) * (32 * VB_STRIDE);
#pragma unroll
            for (int kt = 0; kt < 2; ++kt)
#pragma unroll
                for (int ct = 0; ct < 4; ++ct)
#pragma unroll
                    for (int r = 0; r < 4; ++r)
                        dst[(kt*16 + quad*4 + r)*VB_STRIDE + ct*16 + l15] = acc[kt][ct][r];
            if (lane < 16) {
                suma_buf[(wave - step)*32 + lane]      = suma[0];
                suma_buf[(wave - step)*32 + lane + 16] = suma[1];
            }
        }
        __syncthreads();
        if (wave < step) {
            const float* src = vbuf + wave * (32 * VB_STRIDE);
#pragma unroll
            for (int kt = 0; kt < 2; ++kt)
#pragma unroll
                for (int ct = 0; ct < 4; ++ct)
#pragma unroll
                    for (int r = 0; r < 4; ++r)
                        acc[kt][ct][r] += src[(kt*16 + quad*4 + r)*VB_STRIDE + ct*16 + l15];
            suma[0] += suma_buf[wave*32 + l15];
            suma[1] += suma_buf[wave*32 + l15 + 16];
        }
        __syncthreads();
    }

    // wave 0: write block partial {v (32x64), suma (32)} to workspace
    if (wave == 0) {
        float* wp = ws + (size_t)bid * WS_STRIDE;
#pragma unroll
        for (int kt = 0; kt < 2; ++kt)
#pragma unroll
            for (int r = 0; r < 4; ++r) {
                const int k = kt*16 + quad*4 + r;
#pragma unroll
                for (int ct = 0; ct < 4; ++ct)
                    wp[k*64 + ct*16 + l15] = acc[kt][ct][r];
            }
        if (lane < 16) {
            wp[2048 + lane]      = suma[0];
            wp[2048 + 16 + lane] = suma[1];
        }
    }
}

// Kernel 2: combine the eight N-slices and apply  v - suma[k]*cent[k][c].
__global__ __launch_bounds__(512)
void netvlad_combine(const float* __restrict__ ws,
                     const float* __restrict__ cent,
                     float* __restrict__ out)
{
    const int m   = blockIdx.x;
    const int tid = threadIdx.x;
    const float* pb = ws + (size_t)(8*m) * WS_STRIDE;

    const int k  = tid >> 4;
    const int c0 = (tid & 15) << 2;
    const int off = k*64 + c0;

    float s = 0.f;
    float4 v = {0.f, 0.f, 0.f, 0.f};
#pragma unroll
    for (int i = 0; i < 8; ++i) {
        const float* p = pb + (size_t)i * WS_STRIDE;
        s += p[2048 + k];
        const float4 vi = *(const float4*)(p + off);
        v.x += vi.x; v.y += vi.y; v.z += vi.z; v.w += vi.w;
    }

    const float4 cv = *(const float4*)(cent + off);
    float4 o;
    o.x = v.x - s * cv.x;
    o.y = v.y - s * cv.y;
    o.z = v.z - s * cv.z;
    o.w = v.w - s * cv.w;
    *(float4*)(out + (size_t)m * 2048 + off) = o;
}

extern "C" void kernel_launch(void* const* d_in, const int* in_sizes, int n_in,
                              void* d_out, int out_size, void* d_ws, size_t ws_size,
                              hipStream_t stream) {
    (void)in_sizes; (void)n_in; (void)out_size; (void)ws_size;
    const float* R = (const float*)d_in[0];   // R_seq (8,32,2048,64) fp32
    const float* W = (const float*)d_in[1];   // W (32,64) fp32
    const float* b = (const float*)d_in[2];   // b (32,) fp32
    const float* c = (const float*)d_in[3];   // centroids (32,64) fp32
    float* out = (float*)d_out;               // (8,32,32,64) fp32
    float* ws  = (float*)d_ws;                // 2048 * 2080 floats = 17 MB partials

    hipLaunchKernelGGL(netvlad_partial, dim3(2048), dim3(256), 0, stream, R, W, b, ws);
    hipLaunchKernelGGL(netvlad_combine, dim3(256), dim3(512), 0, stream, ws, c, out);
}